// Round 1
// baseline (388.539 us; speedup 1.0000x reference)
//
#include <hip/hip_runtime.h>
#include <math.h>

// ---------------------------------------------------------------------------
// Problem: out[b][s] = <v_b| I_{2^s} (x) W (x) I |v_b> / <v_b|v_b>,  s=0..12
// where W = Re(U^H X^4 U), U = 16x16 unitary from 36 weights.
// v: 512 x 65536 fp32.  out: 512 x 13 fp32.
// ws layout (floats): [0..256) W row-major; [256..256+512*14) accumulators:
//   acc[row*14 + s] for s=0..12 = Q_s partials, slot 13 = sum of squares.
// ---------------------------------------------------------------------------

using c2 = float2;
__device__ __forceinline__ c2 cmul(c2 a, c2 b) {
    return make_float2(a.x * b.x - a.y * b.y, a.x * b.y + a.y * b.x);
}
__device__ __forceinline__ c2 cadd(c2 a, c2 b) { return make_float2(a.x + b.x, a.y + b.y); }

// kron element: L[i][j] = prod_q u[q][bit(i)][bit(j)], qubit 0 = MSB
__device__ __forceinline__ c2 kelem(const c2 u[4][2][2], int i, int j) {
    c2 p = cmul(u[0][(i >> 3) & 1][(j >> 3) & 1], u[1][(i >> 2) & 1][(j >> 2) & 1]);
    p = cmul(p, u[2][(i >> 1) & 1][(j >> 1) & 1]);
    p = cmul(p, u[3][i & 1][j & 1]);
    return p;
}

// ring_of_cnot(4) is a basis permutation: x -> f(x). Qubit q <-> index bit (3-q).
// CNOT(0,1): b2^=b3; CNOT(1,2): b1^=b2; CNOT(2,3): b0^=b1; CNOT(3,0): b3^=b0.
__device__ __forceinline__ int fperm(int x) {
    int b3 = (x >> 3) & 1, b2 = (x >> 2) & 1, b1 = (x >> 1) & 1, b0 = x & 1;
    b2 ^= b3; b1 ^= b2; b0 ^= b1; b3 ^= b0;
    return (b3 << 3) | (b2 << 2) | (b1 << 1) | b0;
}

__global__ __launch_bounds__(256) void setup_kernel(const float* __restrict__ weight,
                                                    float* __restrict__ ws) {
    __shared__ c2 ush[3][4][2][2];
    __shared__ c2 A[256], B[256];
    const int t = threadIdx.x;

    if (t < 12) {
        const int r = t / 4, q = t % 4;
        const float a = weight[12 * r + 3 * q + 0];
        const float b = weight[12 * r + 3 * q + 1];
        const float c = weight[12 * r + 3 * q + 2];
        const float ca = cosf(0.5f * a), sa = sinf(0.5f * a);
        const float cc = cosf(0.5f * c), sc = sinf(0.5f * c);
        const c2 e  = make_float2(cosf(0.5f * b), -sinf(0.5f * b)); // exp(-i b/2)
        const c2 eb = make_float2(e.x, -e.y);
        // u = Ry(c) Rz(b) Ry(a)
        ush[r][q][0][0] = make_float2(cc * ca * e.x - sc * sa * eb.x, cc * ca * e.y - sc * sa * eb.y);
        ush[r][q][0][1] = make_float2(-cc * sa * e.x - sc * ca * eb.x, -cc * sa * e.y - sc * ca * eb.y);
        ush[r][q][1][0] = make_float2(sc * ca * e.x + cc * sa * eb.x, sc * ca * e.y + cc * sa * eb.y);
        ush[r][q][1][1] = make_float2(-sc * sa * e.x + cc * ca * eb.x, -sc * sa * e.y + cc * ca * eb.y);
    }
    __syncthreads();

    const int i = t >> 4, j = t & 15;
    // A = L0
    A[t] = kelem(ush[0], i, j);
    __syncthreads();
    // B = ring * A  (row scatter: row f(k) of B = row k of A)
    B[fperm(i) * 16 + j] = A[t];
    __syncthreads();
    // A = L1 * B
    {
        c2 acc = make_float2(0.f, 0.f);
        #pragma unroll
        for (int k = 0; k < 16; ++k) acc = cadd(acc, cmul(kelem(ush[1], i, k), B[k * 16 + j]));
        __syncthreads();
        A[t] = acc;
    }
    __syncthreads();
    B[fperm(i) * 16 + j] = A[t];
    __syncthreads();
    // A = L2 * B = U
    {
        c2 acc = make_float2(0.f, 0.f);
        #pragma unroll
        for (int k = 0; k < 16; ++k) acc = cadd(acc, cmul(kelem(ush[2], i, k), B[k * 16 + j]));
        __syncthreads();
        A[t] = acc;
    }
    __syncthreads();
    // W[i][j] = Re( sum_k conj(U[k][i]) * U[k^15][j] )   (X^{ox4}[k][l]=1 iff l=k^15)
    {
        float wr = 0.f;
        #pragma unroll
        for (int k = 0; k < 16; ++k) {
            const c2 a = A[k * 16 + i];          // U[k][i]
            const c2 b = A[(k ^ 15) * 16 + j];   // U[k^15][j]
            wr += a.x * b.x + a.y * b.y;         // Re(conj(a)*b)
        }
        ws[t] = wr;
    }
    // zero accumulators (ws is poisoned 0xAA before every launch)
    for (int z = t; z < 512 * 14; z += 256) ws[256 + z] = 0.f;
}

// ---------------------------------------------------------------------------

__device__ __forceinline__ float wave_sum(float x) {
    #pragma unroll
    for (int off = 32; off > 0; off >>= 1) x += __shfl_down(x, off, 64);
    return x;
}

// q = xv^T W xv ; W rows loaded as float4 (uniform address -> scalar/L1-hit loads)
__device__ __forceinline__ float quadform16(const float4* __restrict__ W4,
                                            const float (&xv)[16]) {
    float q = 0.f;
    #pragma unroll
    for (int i = 0; i < 16; ++i) {
        const float4 wa = W4[i * 4 + 0], wb = W4[i * 4 + 1];
        const float4 wc = W4[i * 4 + 2], wd = W4[i * 4 + 3];
        float y = 0.f;
        y = fmaf(wa.x, xv[0], y);  y = fmaf(wa.y, xv[1], y);
        y = fmaf(wa.z, xv[2], y);  y = fmaf(wa.w, xv[3], y);
        y = fmaf(wb.x, xv[4], y);  y = fmaf(wb.y, xv[5], y);
        y = fmaf(wb.z, xv[6], y);  y = fmaf(wb.w, xv[7], y);
        y = fmaf(wc.x, xv[8], y);  y = fmaf(wc.y, xv[9], y);
        y = fmaf(wc.z, xv[10], y); y = fmaf(wc.w, xv[11], y);
        y = fmaf(wd.x, xv[12], y); y = fmaf(wd.y, xv[13], y);
        y = fmaf(wd.z, xv[14], y); y = fmaf(wd.w, xv[15], y);
        q = fmaf(xv[i], y, q);
    }
    return q;
}

// Pass 1: starts s=4..12 (window in low 12 bits) + sumsq.
// grid = 512 rows * 16 segments; block = 256. Segment (4096 fp32) staged in LDS
// with +1-word-per-16 padding: all strided gathers are <=3-way conflicted.
__global__ __launch_bounds__(256) void pass1_kernel(const float* __restrict__ v,
                                                    const float* __restrict__ ws,
                                                    float* __restrict__ acc) {
    __shared__ float sh[4096 + 256];
    __shared__ float red[4][10];
    const int t = threadIdx.x;
    const int row = blockIdx.x >> 4, seg = blockIdx.x & 15;
    const float* base = v + ((size_t)row << 16) + (seg << 12);

    float ss = 0.f;
    const float4* b4 = (const float4*)base;
    #pragma unroll
    for (int m = 0; m < 4; ++m) {
        const float4 d = b4[m * 256 + t];
        const int e = (m * 256 + t) * 4;      // e%16 in {0,4,8,12}: same pad for all 4
        const int a0 = e + (e >> 4);
        sh[a0 + 0] = d.x; sh[a0 + 1] = d.y; sh[a0 + 2] = d.z; sh[a0 + 3] = d.w;
        ss = fmaf(d.x, d.x, ss); ss = fmaf(d.y, d.y, ss);
        ss = fmaf(d.z, d.z, ss); ss = fmaf(d.w, d.w, ss);
    }
    __syncthreads();

    const float4* W4 = (const float4*)ws;
    float qv[9];
    for (int k = 0; k < 9; ++k) {             // s = 4+k  (rolled: small I$ footprint)
        asm volatile("" ::: "memory");        // stop LICM from hoisting all W loads
        const int s = 4 + k;
        const int st = 1 << (12 - s);
        const int a = t >> (12 - s);
        const int d = t & (st - 1);
        const int eb = a * (st << 4) + d;
        float xv[16];
        #pragma unroll
        for (int kk = 0; kk < 16; ++kk) {
            const int e = eb + kk * st;
            xv[kk] = sh[e + (e >> 4)];
        }
        qv[k] = quadform16(W4, xv);
    }

    const int wave = t >> 6, lane = t & 63;
    #pragma unroll
    for (int k = 0; k < 9; ++k) {
        const float w = wave_sum(qv[k]);
        if (lane == 0) red[wave][k] = w;
    }
    {
        const float w = wave_sum(ss);
        if (lane == 0) red[wave][9] = w;
    }
    __syncthreads();
    if (t < 10) {
        const float tot = red[0][t] + red[1][t] + red[2][t] + red[3][t];
        const int slot = (t == 9) ? 13 : (4 + t);
        atomicAdd(&acc[row * 14 + slot], tot);
    }
}

// Pass 2: starts s=0..3 (window in index bits [9..15]). Column u = bits[15..9]
// (stride 512), 128 elements per column. Block stages a 128u x 64c fp32 tile
// (32 KB) in LDS, layout xs[u*64+col] -> all gathers conflict-free.
// 256 threads: col = t&63, s = t>>6 (one wave per start).
__global__ __launch_bounds__(256) void pass2_kernel(const float* __restrict__ v,
                                                    const float* __restrict__ ws,
                                                    float* __restrict__ acc) {
    __shared__ float xs[128 * 64];
    const int t = threadIdx.x;
    const int row = blockIdx.x >> 3;
    const int c0 = (blockIdx.x & 7) << 6;
    const float* base = v + ((size_t)row << 16) + c0;

    #pragma unroll
    for (int m = 0; m < 32; ++m) {
        const int flat = m * 256 + t;         // = u*64 + col
        const int u = flat >> 6, col = flat & 63;
        xs[flat] = base[u * 512 + col];       // lanes -> consecutive col: coalesced
    }
    __syncthreads();

    const int s = t >> 6;                     // 0..3, uniform per wave
    const int col = t & 63;
    const int sha = 3 - s;
    const int stu = 1 << sha;                 // group stride in u-space
    const float4* W4 = (const float4*)ws;

    float q = 0.f;
    for (int g = 0; g < 8; ++g) {
        asm volatile("" ::: "memory");
        const int a = g >> sha, d = g & (stu - 1);
        const int ub = a * (stu << 4) + d;
        float xv[16];
        #pragma unroll
        for (int kk = 0; kk < 16; ++kk)
            xv[kk] = xs[((ub + kk * stu) << 6) + col];
        q += quadform16(W4, xv);
    }

    const float w = wave_sum(q);
    if ((t & 63) == 0) atomicAdd(&acc[row * 14 + s], w);
}

__global__ __launch_bounds__(256) void finalize_kernel(const float* __restrict__ acc,
                                                       float* __restrict__ out) {
    const int idx = blockIdx.x * 256 + threadIdx.x;
    if (idx < 512 * 13) {
        const int row = idx / 13, s = idx % 13;
        out[idx] = acc[row * 14 + s] / acc[row * 14 + 13];
    }
}

extern "C" void kernel_launch(void* const* d_in, const int* in_sizes, int n_in,
                              void* d_out, int out_size, void* d_ws, size_t ws_size,
                              hipStream_t stream) {
    const float* vb = (const float*)d_in[0];     // (512, 65536) fp32
    const float* wt = (const float*)d_in[1];     // (36,) fp32
    float* out = (float*)d_out;                  // (512, 13) fp32
    float* ws = (float*)d_ws;
    float* acc = ws + 256;

    setup_kernel<<<1, 256, 0, stream>>>(wt, ws);
    pass1_kernel<<<512 * 16, 256, 0, stream>>>(vb, ws, acc);
    pass2_kernel<<<512 * 8, 256, 0, stream>>>(vb, ws, acc);
    finalize_kernel<<<26, 256, 0, stream>>>(acc, out);
}

// Round 2
// 269.013 us; speedup vs baseline: 1.4443x; 1.4443x over previous
//
#include <hip/hip_runtime.h>
#include <math.h>

// ---------------------------------------------------------------------------
// out[b][s] = <v_b| I_{2^s} (x) W (x) I |v_b> / <v_b|v_b>,  s=0..12
// W = Re(U^H X^4 U) (16x16 real symmetric), U from 36 weights.
// MFMA formulation: Q_s = <W, G_s>, G_s = sum_groups x x^T (Gram), computed by
// mfma_f32_16x16x32_bf16 with K = group index. Split precision:
//   x = xh + xl, lo2 = bf16(2*(x-xh));  C += Xh Xh^T + Xh (2Xl)^T
//   => <W,C> = x^T W x + O(2^-17)   (W symmetric; Xl Xl^T term dropped)
// Both A and B fragments are the SAME registers (element lane&15 over 8
// consecutive groups) -> one ds_read_b128 per fragment.
// ws layout (floats): [0..256) W row-major; [256..) acc[row*14+s], slot13=sumsq
// ---------------------------------------------------------------------------

typedef short bf16x8 __attribute__((ext_vector_type(8)));
typedef float f32x4 __attribute__((ext_vector_type(4)));
#define MFMA16(a, b, c) __builtin_amdgcn_mfma_f32_16x16x32_bf16((a), (b), (c), 0, 0, 0)

union FragU { unsigned int u[4]; bf16x8 v; };

__device__ __forceinline__ int swz(int ge) { return ge ^ (ge >> 5); }

__device__ __forceinline__ unsigned short f2bf(float f) {   // RNE truncate
    unsigned int u = __float_as_uint(f);
    u += 0x7fffu + ((u >> 16) & 1u);
    return (unsigned short)(u >> 16);
}
__device__ __forceinline__ float bf2f(unsigned short h) {
    return __uint_as_float(((unsigned int)h) << 16);
}

__device__ __forceinline__ float wave_sum(float x) {
    #pragma unroll
    for (int off = 32; off > 0; off >>= 1) x += __shfl_down(x, off, 64);
    return x;
}

// ------------------------- setup: build W on device -------------------------
using c2 = float2;
__device__ __forceinline__ c2 cmul(c2 a, c2 b) {
    return make_float2(a.x * b.x - a.y * b.y, a.x * b.y + a.y * b.x);
}
__device__ __forceinline__ c2 cadd(c2 a, c2 b) { return make_float2(a.x + b.x, a.y + b.y); }

__device__ __forceinline__ c2 kelem(const c2 u[4][2][2], int i, int j) {
    c2 p = cmul(u[0][(i >> 3) & 1][(j >> 3) & 1], u[1][(i >> 2) & 1][(j >> 2) & 1]);
    p = cmul(p, u[2][(i >> 1) & 1][(j >> 1) & 1]);
    p = cmul(p, u[3][i & 1][j & 1]);
    return p;
}
__device__ __forceinline__ int fperm(int x) {
    int b3 = (x >> 3) & 1, b2 = (x >> 2) & 1, b1 = (x >> 1) & 1, b0 = x & 1;
    b2 ^= b3; b1 ^= b2; b0 ^= b1; b3 ^= b0;
    return (b3 << 3) | (b2 << 2) | (b1 << 1) | b0;
}

__global__ __launch_bounds__(256) void setup_kernel(const float* __restrict__ weight,
                                                    float* __restrict__ ws) {
    __shared__ c2 ush[3][4][2][2];
    __shared__ c2 A[256], B[256];
    const int t = threadIdx.x;

    if (t < 12) {
        const int r = t / 4, q = t % 4;
        const float a = weight[12 * r + 3 * q + 0];
        const float b = weight[12 * r + 3 * q + 1];
        const float c = weight[12 * r + 3 * q + 2];
        const float ca = cosf(0.5f * a), sa = sinf(0.5f * a);
        const float cc = cosf(0.5f * c), sc = sinf(0.5f * c);
        const c2 e = make_float2(cosf(0.5f * b), -sinf(0.5f * b));
        const c2 eb = make_float2(e.x, -e.y);
        ush[r][q][0][0] = make_float2(cc * ca * e.x - sc * sa * eb.x, cc * ca * e.y - sc * sa * eb.y);
        ush[r][q][0][1] = make_float2(-cc * sa * e.x - sc * ca * eb.x, -cc * sa * e.y - sc * ca * eb.y);
        ush[r][q][1][0] = make_float2(sc * ca * e.x + cc * sa * eb.x, sc * ca * e.y + cc * sa * eb.y);
        ush[r][q][1][1] = make_float2(-sc * sa * e.x + cc * ca * eb.x, -sc * sa * e.y + cc * ca * eb.y);
    }
    __syncthreads();

    const int i = t >> 4, j = t & 15;
    A[t] = kelem(ush[0], i, j);
    __syncthreads();
    B[fperm(i) * 16 + j] = A[t];
    __syncthreads();
    {
        c2 acc = make_float2(0.f, 0.f);
        #pragma unroll
        for (int k = 0; k < 16; ++k) acc = cadd(acc, cmul(kelem(ush[1], i, k), B[k * 16 + j]));
        __syncthreads();
        A[t] = acc;
    }
    __syncthreads();
    B[fperm(i) * 16 + j] = A[t];
    __syncthreads();
    {
        c2 acc = make_float2(0.f, 0.f);
        #pragma unroll
        for (int k = 0; k < 16; ++k) acc = cadd(acc, cmul(kelem(ush[2], i, k), B[k * 16 + j]));
        __syncthreads();
        A[t] = acc;
    }
    __syncthreads();
    {
        float wr = 0.f;
        #pragma unroll
        for (int k = 0; k < 16; ++k) {
            const c2 a = A[k * 16 + i];
            const c2 b = A[(k ^ 15) * 16 + j];
            wr += a.x * b.x + a.y * b.y;
        }
        ws[t] = wr;
    }
    for (int z = t; z < 512 * 14; z += 256) ws[256 + z] = 0.f;
}

// --------------------------- pass 1: s = 4..12 ------------------------------
// One block per (row, 4096-elem segment). Natural swizzled bf16 layout serves
// s=4..9 (b128), s=10 (2xb64), s=11 (4xb32); i-major transposed copy for s=12.
__global__ __launch_bounds__(256) void pass1_kernel(const float* __restrict__ v,
                                                    const float* __restrict__ ws,
                                                    float* __restrict__ accg) {
    __shared__ unsigned short nh[4096], nl[4096];
    __shared__ unsigned short th[4096], tl[4096];
    __shared__ float Wl[256];
    const int t = threadIdx.x;
    const int row = blockIdx.x >> 4, seg = blockIdx.x & 15;
    const float4* b4 = (const float4*)(v + ((size_t)row << 16) + (seg << 12));
    Wl[t] = ws[t];

    float ss = 0.f;
    #pragma unroll
    for (int m = 0; m < 4; ++m) {
        const float4 d = b4[m * 256 + t];
        ss = fmaf(d.x, d.x, ss); ss = fmaf(d.y, d.y, ss);
        ss = fmaf(d.z, d.z, ss); ss = fmaf(d.w, d.w, ss);
        const unsigned short h0 = f2bf(d.x), h1 = f2bf(d.y), h2 = f2bf(d.z), h3 = f2bf(d.w);
        const unsigned short l0 = f2bf(2.f * (d.x - bf2f(h0)));
        const unsigned short l1 = f2bf(2.f * (d.y - bf2f(h1)));
        const unsigned short l2 = f2bf(2.f * (d.z - bf2f(h2)));
        const unsigned short l3 = f2bf(2.f * (d.w - bf2f(h3)));
        const unsigned int sh01 = h0 | ((unsigned)h1 << 16), sh23 = h2 | ((unsigned)h3 << 16);
        const unsigned int sl01 = l0 | ((unsigned)l1 << 16), sl23 = l2 | ((unsigned)l3 << 16);

        // natural layout (16B-granule XOR swizzle)
        const int e0 = (m * 256 + t) * 4;
        const int idx = (swz(e0 >> 3) << 3) + (e0 & 7);
        *(uint2*)&nh[idx] = make_uint2(sh01, sh23);
        *(uint2*)&nl[idx] = make_uint2(sl01, sl23);

        // s=12 transposed copy T[i*256+g]; pair (g,g^1) via shfl_xor(4) -> b32
        const int g = e0 >> 4;              // group for s=12
        const int i0 = e0 & 15;             // 4*(t&3)
        const unsigned int ph01 = __shfl_xor(sh01, 4);
        const unsigned int ph23 = __shfl_xor(sh23, 4);
        const unsigned int pl01 = __shfl_xor(sl01, 4);
        const unsigned int pl23 = __shfl_xor(sl23, 4);
        const int gev = g & ~1;
        unsigned int wh0, wh1, wl0, wl1;
        int ia, ib;
        if ((t & 4) == 0) {                 // self holds even g: r = 0,1
            ia = i0; ib = i0 + 1;
            wh0 = (sh01 & 0xffffu) | (ph01 << 16);
            wh1 = (sh01 >> 16) | (ph01 & 0xffff0000u);
            wl0 = (sl01 & 0xffffu) | (pl01 << 16);
            wl1 = (sl01 >> 16) | (pl01 & 0xffff0000u);
        } else {                            // self holds odd g: r = 2,3
            ia = i0 + 2; ib = i0 + 3;
            wh0 = (ph23 & 0xffffu) | (sh23 << 16);
            wh1 = (ph23 >> 16) | (sh23 & 0xffff0000u);
            wl0 = (pl23 & 0xffffu) | (sl23 << 16);
            wl1 = (pl23 >> 16) | (sl23 & 0xffff0000u);
        }
        const int ea = (ia << 8) + gev, ebi = (ib << 8) + gev;
        const int wa = (swz(ea >> 3) << 2) + ((gev & 7) >> 1);
        const int wb = (swz(ebi >> 3) << 2) + ((gev & 7) >> 1);
        ((unsigned int*)th)[wa] = wh0; ((unsigned int*)th)[wb] = wh1;
        ((unsigned int*)tl)[wa] = wl0; ((unsigned int*)tl)[wb] = wl1;
    }
    {
        const float s2 = wave_sum(ss);
        if ((t & 63) == 0) atomicAdd(&accg[row * 14 + 13], s2);
    }
    __syncthreads();

    const int l = t & 63, wvi = t >> 6;
    const int i = l & 15, h = l >> 4;

    for (int si = wvi; si < 9; si += 4) {   // wave0: s=4,8,12; w1: 5,9; w2: 6,10; w3: 7,11
        const int s = 4 + si;
        f32x4 a1 = {0.f, 0.f, 0.f, 0.f}, a2 = {0.f, 0.f, 0.f, 0.f};
        if (s <= 9) {
            const int lst = 12 - s;
            #pragma unroll
            for (int c = 0; c < 8; ++c) {
                const int g0 = 32 * c + 8 * h;
                const int a = g0 >> lst, d0 = g0 & ((1 << lst) - 1);
                const int e0 = (a << (lst + 4)) + (i << lst) + d0;   // 8-aligned
                const int idx = swz(e0 >> 3) << 3;
                const bf16x8 fh = *(const bf16x8*)&nh[idx];
                const bf16x8 fl = *(const bf16x8*)&nl[idx];
                a1 = MFMA16(fh, fh, a1);
                a2 = MFMA16(fh, fl, a2);
            }
        } else if (s == 10) {
            #pragma unroll
            for (int c = 0; c < 8; ++c) {
                const int a0 = 8 * c + 2 * h;
                const int e0 = a0 * 64 + 4 * i;
                const int e1 = e0 + 64;
                const int iA = (swz(e0 >> 3) << 3) + (e0 & 7);
                const int iB = (swz(e1 >> 3) << 3) + (e1 & 7);
                FragU fh, fl; uint2 p;
                p = *(const uint2*)&nh[iA]; fh.u[0] = p.x; fh.u[1] = p.y;
                p = *(const uint2*)&nh[iB]; fh.u[2] = p.x; fh.u[3] = p.y;
                p = *(const uint2*)&nl[iA]; fl.u[0] = p.x; fl.u[1] = p.y;
                p = *(const uint2*)&nl[iB]; fl.u[2] = p.x; fl.u[3] = p.y;
                a1 = MFMA16(fh.v, fh.v, a1);
                a2 = MFMA16(fh.v, fl.v, a2);
            }
        } else if (s == 11) {
            #pragma unroll
            for (int c = 0; c < 8; ++c) {
                FragU fh, fl;
                #pragma unroll
                for (int p2 = 0; p2 < 4; ++p2) {
                    const int ap = 16 * c + 4 * h + p2;
                    const int e0 = ap * 32 + 2 * i;
                    const int ix = (swz(e0 >> 3) << 3) + (e0 & 7);
                    fh.u[p2] = *(const unsigned int*)&nh[ix];
                    fl.u[p2] = *(const unsigned int*)&nl[ix];
                }
                a1 = MFMA16(fh.v, fh.v, a1);
                a2 = MFMA16(fh.v, fl.v, a2);
            }
        } else {  // s == 12: i-major transposed copy
            #pragma unroll
            for (int c = 0; c < 8; ++c) {
                const int el = (i << 8) + 32 * c + 8 * h;
                const int idx = swz(el >> 3) << 3;
                const bf16x8 fh = *(const bf16x8*)&th[idx];
                const bf16x8 fl = *(const bf16x8*)&tl[idx];
                a1 = MFMA16(fh, fh, a1);
                a2 = MFMA16(fh, fl, a2);
            }
        }
        // Q_s partial = <W, C>; lane holds C rows 4h+0..3, col i (layout-swap
        // immune: W and C both symmetric). W[col][4h+r] contiguous -> b128.
        const float4 wr = *(const float4*)&Wl[(i << 4) + (h << 2)];
        float q = wr.x * (a1[0] + a2[0]) + wr.y * (a1[1] + a2[1])
                + wr.z * (a1[2] + a2[2]) + wr.w * (a1[3] + a2[3]);
        q = wave_sum(q);
        if (l == 0) atomicAdd(&accg[row * 14 + s], q);
    }
}

// ---------------------------- pass 2: s = 0..3 ------------------------------
// Window lives in index bits 9..15 (u). Block = (row, 64-col tile). Columns are
// the MFMA K fast axis -> natural xs[u*64+col] layout (col-block XOR swizzle)
// gives contiguous b128 fragments for every s.
__global__ __launch_bounds__(256) void pass2_kernel(const float* __restrict__ v,
                                                    const float* __restrict__ ws,
                                                    float* __restrict__ accg) {
    __shared__ unsigned short xh[8192], xl[8192];
    __shared__ float Wl[256];
    const int t = threadIdx.x;
    const int row = blockIdx.x >> 3;
    const int c0 = (blockIdx.x & 7) << 6;
    const float* base = v + ((size_t)row << 16) + c0;
    Wl[t] = ws[t];

    #pragma unroll
    for (int it = 0; it < 8; ++it) {
        const int u = it * 16 + (t >> 4);
        const int col0 = (t & 15) << 2;
        const float4 d = *(const float4*)(base + u * 512 + col0);
        const unsigned short h0 = f2bf(d.x), h1 = f2bf(d.y), h2 = f2bf(d.z), h3 = f2bf(d.w);
        const unsigned short l0 = f2bf(2.f * (d.x - bf2f(h0)));
        const unsigned short l1 = f2bf(2.f * (d.y - bf2f(h1)));
        const unsigned short l2 = f2bf(2.f * (d.z - bf2f(h2)));
        const unsigned short l3 = f2bf(2.f * (d.w - bf2f(h3)));
        const int blkS = ((col0 >> 3) ^ u ^ (u >> 3)) & 7;
        const int idx = u * 64 + blkS * 8 + (col0 & 7);
        *(uint2*)&xh[idx] = make_uint2(h0 | ((unsigned)h1 << 16), h2 | ((unsigned)h3 << 16));
        *(uint2*)&xl[idx] = make_uint2(l0 | ((unsigned)l1 << 16), l2 | ((unsigned)l3 << 16));
    }
    __syncthreads();

    const int l = t & 63, s = t >> 6;       // one wave per start
    const int i = l & 15, h = l >> 4;
    const int sh3 = 3 - s;                  // log2(stu)
    f32x4 a1 = {0.f, 0.f, 0.f, 0.f}, a2 = {0.f, 0.f, 0.f, 0.f};
    #pragma unroll
    for (int cc = 0; cc < 16; ++cc) {
        const int ad = cc >> 1;
        const int a = ad >> sh3, dd = ad & ((1 << sh3) - 1);
        const int ui = (a << (sh3 + 4)) + (i << sh3) + dd;
        const int blk = ((cc & 1) << 2) + h;
        const int blkS = (blk ^ ui ^ (ui >> 3)) & 7;
        const int idx = ui * 64 + blkS * 8;
        const bf16x8 fh = *(const bf16x8*)&xh[idx];
        const bf16x8 fl = *(const bf16x8*)&xl[idx];
        a1 = MFMA16(fh, fh, a1);
        a2 = MFMA16(fh, fl, a2);
    }
    const float4 wr = *(const float4*)&Wl[(i << 4) + (h << 2)];
    float q = wr.x * (a1[0] + a2[0]) + wr.y * (a1[1] + a2[1])
            + wr.z * (a1[2] + a2[2]) + wr.w * (a1[3] + a2[3]);
    q = wave_sum(q);
    if (l == 0) atomicAdd(&accg[row * 14 + s], q);
}

__global__ __launch_bounds__(256) void finalize_kernel(const float* __restrict__ acc,
                                                       float* __restrict__ out) {
    const int idx = blockIdx.x * 256 + threadIdx.x;
    if (idx < 512 * 13) {
        const int row = idx / 13, s = idx % 13;
        out[idx] = acc[row * 14 + s] / acc[row * 14 + 13];
    }
}

extern "C" void kernel_launch(void* const* d_in, const int* in_sizes, int n_in,
                              void* d_out, int out_size, void* d_ws, size_t ws_size,
                              hipStream_t stream) {
    const float* vb = (const float*)d_in[0];
    const float* wt = (const float*)d_in[1];
    float* out = (float*)d_out;
    float* ws = (float*)d_ws;
    float* acc = ws + 256;

    setup_kernel<<<1, 256, 0, stream>>>(wt, ws);
    pass1_kernel<<<512 * 16, 256, 0, stream>>>(vb, ws, acc);
    pass2_kernel<<<512 * 8, 256, 0, stream>>>(vb, ws, acc);
    finalize_kernel<<<26, 256, 0, stream>>>(acc, out);
}

// Round 3
// 208.929 us; speedup vs baseline: 1.8597x; 1.2876x over previous
//
#include <hip/hip_runtime.h>
#include <math.h>

// ---------------------------------------------------------------------------
// out[b][s] = <v_b| I_{2^s} (x) W (x) I |v_b> / <v_b|v_b>,  s=0..12
// W = Re(U^H X^4 U) (16x16 real symmetric), U from 36 weights.
// Q_s = <W, G_s>, G_s = sum_groups x x^T via mfma_f32_16x16x32_f16 (K=groups).
// fp16 RNE inputs, fp32 accum: out-error ~2e-5 << 3.2e-4 threshold.
// Window partition: s=3..11 from contiguous 8192-elem tiles (bits 0..12);
// s=0,1,2,12 from col-major 128u x 64c tiles (u = bits 9..15, u-fast layout).
// ws layout (floats): [0..256) W row-major; [256..) acc[row*14+s], slot13=sumsq
// ---------------------------------------------------------------------------

typedef _Float16 f16x8 __attribute__((ext_vector_type(8)));
typedef float f32x4 __attribute__((ext_vector_type(4)));
#define MFMAH(a, b, c) __builtin_amdgcn_mfma_f32_16x16x32_f16((a), (b), (c), 0, 0, 0)

union H4 { _Float16 h[4]; uint2 q; };
union Frag { _Float16 h[8]; f16x8 v; uint2 q[2]; unsigned int w[4]; };

__device__ __forceinline__ int swz(int g) { return g ^ (g >> 5); }

__device__ __forceinline__ float wave_sum(float x) {
    #pragma unroll
    for (int off = 32; off > 0; off >>= 1) x += __shfl_down(x, off, 64);
    return x;
}

// ------------------------- setup: build W on device -------------------------
using c2 = float2;
__device__ __forceinline__ c2 cmul(c2 a, c2 b) {
    return make_float2(a.x * b.x - a.y * b.y, a.x * b.y + a.y * b.x);
}
__device__ __forceinline__ c2 cadd(c2 a, c2 b) { return make_float2(a.x + b.x, a.y + b.y); }

__device__ __forceinline__ c2 kelem(const c2 u[4][2][2], int i, int j) {
    c2 p = cmul(u[0][(i >> 3) & 1][(j >> 3) & 1], u[1][(i >> 2) & 1][(j >> 2) & 1]);
    p = cmul(p, u[2][(i >> 1) & 1][(j >> 1) & 1]);
    p = cmul(p, u[3][i & 1][j & 1]);
    return p;
}
__device__ __forceinline__ int fperm(int x) {
    int b3 = (x >> 3) & 1, b2 = (x >> 2) & 1, b1 = (x >> 1) & 1, b0 = x & 1;
    b2 ^= b3; b1 ^= b2; b0 ^= b1; b3 ^= b0;
    return (b3 << 3) | (b2 << 2) | (b1 << 1) | b0;
}

__global__ __launch_bounds__(256) void setup_kernel(const float* __restrict__ weight,
                                                    float* __restrict__ ws) {
    __shared__ c2 ush[3][4][2][2];
    __shared__ c2 A[256], B[256];
    const int t = threadIdx.x;

    if (t < 12) {
        const int r = t / 4, q = t % 4;
        const float a = weight[12 * r + 3 * q + 0];
        const float b = weight[12 * r + 3 * q + 1];
        const float c = weight[12 * r + 3 * q + 2];
        const float ca = cosf(0.5f * a), sa = sinf(0.5f * a);
        const float cc = cosf(0.5f * c), sc = sinf(0.5f * c);
        const c2 e = make_float2(cosf(0.5f * b), -sinf(0.5f * b));
        const c2 eb = make_float2(e.x, -e.y);
        ush[r][q][0][0] = make_float2(cc * ca * e.x - sc * sa * eb.x, cc * ca * e.y - sc * sa * eb.y);
        ush[r][q][0][1] = make_float2(-cc * sa * e.x - sc * ca * eb.x, -cc * sa * e.y - sc * ca * eb.y);
        ush[r][q][1][0] = make_float2(sc * ca * e.x + cc * sa * eb.x, sc * ca * e.y + cc * sa * eb.y);
        ush[r][q][1][1] = make_float2(-sc * sa * e.x + cc * ca * eb.x, -sc * sa * e.y + cc * ca * eb.y);
    }
    __syncthreads();

    const int i = t >> 4, j = t & 15;
    A[t] = kelem(ush[0], i, j);
    __syncthreads();
    B[fperm(i) * 16 + j] = A[t];
    __syncthreads();
    {
        c2 acc = make_float2(0.f, 0.f);
        #pragma unroll
        for (int k = 0; k < 16; ++k) acc = cadd(acc, cmul(kelem(ush[1], i, k), B[k * 16 + j]));
        __syncthreads();
        A[t] = acc;
    }
    __syncthreads();
    B[fperm(i) * 16 + j] = A[t];
    __syncthreads();
    {
        c2 acc = make_float2(0.f, 0.f);
        #pragma unroll
        for (int k = 0; k < 16; ++k) acc = cadd(acc, cmul(kelem(ush[2], i, k), B[k * 16 + j]));
        __syncthreads();
        A[t] = acc;
    }
    __syncthreads();
    {
        float wr = 0.f;
        #pragma unroll
        for (int k = 0; k < 16; ++k) {
            const c2 a = A[k * 16 + i];
            const c2 b = A[(k ^ 15) * 16 + j];
            wr += a.x * b.x + a.y * b.y;
        }
        ws[t] = wr;
    }
    for (int z = t; z < 512 * 14; z += 256) ws[256 + z] = 0.f;
}

// ------------------------------ fused main ----------------------------------
// blocks [0, 4096):    contiguous-tile path, s = 3..11 + sumsq
// blocks [4096, 8192): col-major-tile path, s = 0,1,2,12
__global__ __launch_bounds__(256, 6) void main_kernel(const float* __restrict__ v,
                                                      const float* __restrict__ ws,
                                                      float* __restrict__ accg) {
    __shared__ unsigned short sh16[8192];   // fp16 tile (both paths, 16 KB)
    __shared__ float Wl[256];
    const int t = threadIdx.x;
    const int l = t & 63, wv = t >> 6;
    const int i = l & 15, h = l >> 4;
    Wl[t] = ws[t];

    if (blockIdx.x < 4096) {
        // ---------------- contiguous path: s = 3..11 ----------------
        const int row = blockIdx.x >> 3, seg = blockIdx.x & 7;
        const float4* b4 = (const float4*)(v + ((size_t)row << 16) + (seg << 13));

        float ss = 0.f;
        #pragma unroll
        for (int m = 0; m < 8; ++m) {
            const float4 d = b4[m * 256 + t];
            ss = fmaf(d.x, d.x, ss); ss = fmaf(d.y, d.y, ss);
            ss = fmaf(d.z, d.z, ss); ss = fmaf(d.w, d.w, ss);
            H4 p;
            p.h[0] = (_Float16)d.x; p.h[1] = (_Float16)d.y;
            p.h[2] = (_Float16)d.z; p.h[3] = (_Float16)d.w;
            const int e0 = (m * 256 + t) * 4;                 // 4-aligned
            const int idx = (swz(e0 >> 3) << 3) + (e0 & 7);   // b64, conflict-free
            *(uint2*)&sh16[idx] = p.q;
        }
        {
            const float s2 = wave_sum(ss);
            if (l == 0) atomicAdd(&accg[row * 14 + 13], s2);
        }
        __syncthreads();

        // 9 s-units x 16 K-iters = 144, wave wv owns f = 36*wv .. +35
        int f = 36 * wv;
        const int fend = f + 36;
        while (f < fend) {
            const int sidx = f >> 4;            // 0..8 -> s = 3+sidx
            const int s = 3 + sidx;
            const int bnd = (sidx + 1) << 4;
            const int cstop = (bnd < fend) ? bnd : fend;
            const int lst = 12 - s;
            f32x4 acc = {0.f, 0.f, 0.f, 0.f};
            if (s <= 9) {
                #pragma unroll 4
                for (int ff = f; ff < cstop; ++ff) {
                    const int g0 = 32 * (ff & 15) + 8 * h;
                    const int a = g0 >> lst, d0 = g0 & ((1 << lst) - 1);
                    const int e0 = (a << (lst + 4)) + (i << lst) + d0;  // 8-aligned
                    const f16x8 fh = *(const f16x8*)&sh16[swz(e0 >> 3) << 3];
                    acc = MFMAH(fh, fh, acc);
                }
            } else if (s == 10) {
                #pragma unroll 4
                for (int ff = f; ff < cstop; ++ff) {
                    const int a0 = 8 * (ff & 15) + 2 * h;     // g0>>2
                    const int ea = a0 * 64 + 4 * i;
                    const int eb = ea + 64;
                    Frag fr;
                    fr.q[0] = *(const uint2*)&sh16[(swz(ea >> 3) << 3) + (ea & 7)];
                    fr.q[1] = *(const uint2*)&sh16[(swz(eb >> 3) << 3) + (eb & 7)];
                    acc = MFMAH(fr.v, fr.v, acc);
                }
            } else {            // s == 11
                #pragma unroll 4
                for (int ff = f; ff < cstop; ++ff) {
                    const int a0 = 16 * (ff & 15) + 4 * h;    // g0>>1
                    Frag fr;
                    #pragma unroll
                    for (int p = 0; p < 4; ++p) {
                        const int e = (a0 + p) * 32 + 2 * i;
                        fr.w[p] = *(const unsigned int*)&sh16[(swz(e >> 3) << 3) + (e & 7)];
                    }
                    acc = MFMAH(fr.v, fr.v, acc);
                }
            }
            const float4 wr = *(const float4*)&Wl[(i << 4) + (h << 2)];
            float q = wr.x * acc[0] + wr.y * acc[1] + wr.z * acc[2] + wr.w * acc[3];
            q = wave_sum(q);
            if (l == 0) atomicAdd(&accg[row * 14 + s], q);
            f = cstop;
        }
    } else {
        // ------------- col-major path: s = 0,1,2,12 -------------
        // tile: u = bits 9..15 (128 values, stride 512), cols c0..c0+63.
        // LDS layout: sh16[c*128 + (u ^ 8*(c&15))]  (u-fast, granule-XOR swizzle)
        const int bi = blockIdx.x - 4096;
        const int row = bi >> 3;
        const int c0 = (bi & 7) << 6;
        const float* bp = v + ((size_t)row << 16) + c0 + l;   // lane -> column

        #pragma unroll
        for (int m = 0; m < 8; ++m) {
            const int u0 = 32 * wv + 4 * m;                    // wave covers 32 u's
            H4 p;
            p.h[0] = (_Float16)bp[(u0 + 0) * 512];
            p.h[1] = (_Float16)bp[(u0 + 1) * 512];
            p.h[2] = (_Float16)bp[(u0 + 2) * 512];
            p.h[3] = (_Float16)bp[(u0 + 3) * 512];
            *(uint2*)&sh16[l * 128 + (u0 ^ (8 * (l & 15)))] = p.q;  // b64, conflict-free
        }
        __syncthreads();

        f32x4 acc = {0.f, 0.f, 0.f, 0.f};
        int s;
        if (wv == 0) {          // s=0: window = u-bits 3..6; K = (col, u-low3)
            s = 0;
            #pragma unroll 4
            for (int cc = 0; cc < 16; ++cc) {
                const int cl = 4 * cc + h;
                const f16x8 fh = *(const f16x8*)&sh16[cl * 128 + ((8 * i) ^ (8 * (cl & 15)))];
                acc = MFMAH(fh, fh, acc);
            }
        } else if (wv == 1) {   // s=1: window = u-bits 2..5; frag = 2 x b64
            s = 1;
            #pragma unroll 4
            for (int cc = 0; cc < 16; ++cc) {
                const int cl = 4 * cc + h;
                const int k = 8 * (cl & 15);
                Frag fr;
                fr.q[0] = *(const uint2*)&sh16[cl * 128 + ((4 * i) ^ k)];
                fr.q[1] = *(const uint2*)&sh16[cl * 128 + ((64 + 4 * i) ^ k)];
                acc = MFMAH(fr.v, fr.v, acc);
            }
        } else if (wv == 2) {   // s=2: window = u-bits 1..4; frag = 4 x b32
            s = 2;
            #pragma unroll 4
            for (int cc = 0; cc < 16; ++cc) {
                const int cl = 4 * cc + h;
                const int k = 8 * (cl & 15);
                Frag fr;
                #pragma unroll
                for (int p = 0; p < 4; ++p)
                    fr.w[p] = *(const unsigned int*)&sh16[cl * 128 + ((2 * i + 32 * p) ^ k)];
                acc = MFMAH(fr.v, fr.v, acc);
            }
        } else {                // s=12: window = col bits 0..3; K = (colgrp, u)
            s = 12;
            #pragma unroll 4
            for (int cc = 0; cc < 16; ++cc) {
                const int k0 = 32 * cc + 8 * h;
                const int cg = k0 >> 7, u0 = k0 & 127;        // u0 8-aligned
                const int col = 16 * cg + i;
                const f16x8 fh = *(const f16x8*)&sh16[col * 128 + (u0 ^ (8 * i))];
                acc = MFMAH(fh, fh, acc);
            }
        }
        const float4 wr = *(const float4*)&Wl[(i << 4) + (h << 2)];
        float q = wr.x * acc[0] + wr.y * acc[1] + wr.z * acc[2] + wr.w * acc[3];
        q = wave_sum(q);
        if (l == 0) atomicAdd(&accg[row * 14 + s], q);
    }
}

__global__ __launch_bounds__(256) void finalize_kernel(const float* __restrict__ acc,
                                                       float* __restrict__ out) {
    const int idx = blockIdx.x * 256 + threadIdx.x;
    if (idx < 512 * 13) {
        const int row = idx / 13, s = idx % 13;
        out[idx] = acc[row * 14 + s] / acc[row * 14 + 13];
    }
}

extern "C" void kernel_launch(void* const* d_in, const int* in_sizes, int n_in,
                              void* d_out, int out_size, void* d_ws, size_t ws_size,
                              hipStream_t stream) {
    const float* vb = (const float*)d_in[0];
    const float* wt = (const float*)d_in[1];
    float* out = (float*)d_out;
    float* ws = (float*)d_ws;
    float* acc = ws + 256;

    setup_kernel<<<1, 256, 0, stream>>>(wt, ws);
    main_kernel<<<8192, 256, 0, stream>>>(vb, ws, acc);
    finalize_kernel<<<26, 256, 0, stream>>>(acc, out);
}